// Round 12
// baseline (186.051 us; speedup 1.0000x reference)
//
#include <hip/hip_runtime.h>

#define B_DIM 32
#define T_DIM 8192
#define C_DIM 32
#define N_ELEM (B_DIM * T_DIM * C_DIM)      /* 8388608 */
#define SUM_PT 16383
#define BITS_ELEM (B_DIM * SUM_PT * C_DIM)  /* 16776192 */
#define NLEVEL 14
#define PARTW 2048
#define QSCALE 0.17677669529663687f         /* 1/sqrt(32) */
#define ALPHA  70.710678118654755f          /* 4*INV_TEMP/sqrt(32) */

#define OWN 128                              /* 4096-res rows owned per block */
#define HALO 16
#define MAXL (OWN + 2 * HALO)                /* 160 */

__device__ __forceinline__ float entf(float x) { return -(x * __logf(x + 1e-8f)); }
__device__ __forceinline__ float qval(float bit) { return bit * (2.0f * QSCALE) - QSCALE; }

// interp of level-j quant at (possibly half-integer) T-position tpos, packed bit c.
__device__ __forceinline__ float interp_pk(const unsigned int* __restrict__ pkbase,
                                           int ptj, float tpos, int c) {
    const float a = (float)ptj * (1.0f / (float)T_DIM);
    float pos = (tpos + 0.5f) * a - 0.5f;
    pos = fminf(fmaxf(pos, 0.0f), (float)(ptj - 1));
    const int lo = (int)pos;
    const int hi = min(lo + 1, ptj - 1);
    const float w = pos - (float)lo;
    const float b0 = (float)((pkbase[lo] >> c) & 1u);
    const float b1 = (float)((pkbase[hi] >> c) & 1u);
    return ((b0 * (1.0f - w) + b1 * w) * 2.0f - 1.0f) * QSCALE;
}

// interp from a LOCAL packed window (indices proven in-window for owned use).
template <int PTJ>
__device__ __forceinline__ float interp_loc(const unsigned int* __restrict__ bl,
                                            int p0, float tpos, int c) {
    const float a = (float)PTJ * (1.0f / (float)T_DIM);
    float pos = (tpos + 0.5f) * a - 0.5f;
    pos = fminf(fmaxf(pos, 0.0f), (float)(PTJ - 1));
    const int lo = (int)pos;
    const int hi = min(lo + 1, PTJ - 1);
    const float w = pos - (float)lo;
    const float b0 = (float)((bl[lo - p0] >> c) & 1u);
    const float b1 = (float)((bl[hi - p0] >> c) & 1u);
    return ((b0 * (1.0f - w) + b1 * w) * 2.0f - 1.0f) * QSCALE;
}

// Closed-form sum over t in [m*64,(m+1)*64) of float-bits interp, ptj <= 64.
__device__ float pooled_up_sum64(const float* base, int ptj, int m) {
    const int W = 64;
    const float a = (float)ptj * (1.0f / (float)T_DIM);
    const float p0 = ((float)(m * W) + 0.5f) * a - 0.5f;
    const float pmax = (float)(ptj - 1);
    float sum = 0.0f;
    int iL = 0;
    if (p0 < 0.0f) { iL = (int)ceilf(-p0 / a); if (iL > W) iL = W; }
    int iH = W - 1;
    if (p0 + (float)(W - 1) * a > pmax) {
        iH = (int)floorf((pmax - p0) / a);
        if (iH > W - 1) iH = W - 1;
        if (iH < -1) iH = -1;
    }
    if (iL > 0) sum += (float)iL * qval(base[0]);
    if (iH < W - 1) sum += (float)(W - 1 - iH) * qval(base[(size_t)(ptj - 1) * C_DIM]);
    if (iH >= iL) {
        const float pL = p0 + (float)iL * a;
        int l0 = (int)pL;
        if (l0 > ptj - 1) l0 = ptj - 1;
        const int is = (int)ceilf(((float)(l0 + 1) - p0) / a);
        const int endA = min(is - 1, iH);
        if (endA >= iL) {
            const int nA = endA - iL + 1;
            const float sI = 0.5f * (float)(iL + endA) * (float)nA;
            const float SA = (float)nA * (p0 - (float)l0) + a * sI;
            const float q0 = qval(base[(size_t)l0 * C_DIM]);
            const float q1 = qval(base[(size_t)min(l0 + 1, ptj - 1) * C_DIM]);
            sum += (float)nA * q0 + SA * (q1 - q0);
        }
        const int begB = max(is, iL);
        if (begB <= iH) {
            const int nB = iH - begB + 1;
            const float sI = 0.5f * (float)(begB + iH) * (float)nB;
            const float SB = (float)nB * (p0 - (float)(l0 + 1)) + a * sI;
            const float q1 = qval(base[(size_t)min(l0 + 1, ptj - 1) * C_DIM]);
            const float q2 = qval(base[(size_t)min(l0 + 2, ptj - 1) * C_DIM]);
            sum += (float)nB * q1 + SB * (q2 - q1);
        }
    }
    return sum;
}

template <int NT>
__device__ __forceinline__ void write_partials(float eAcc, float cAcc, float pAcc,
                                               float* partial, int level, int col) {
    __shared__ float sP[NT];
    __shared__ float sEC[NT / 16];
    __syncthreads();
    const int grp = threadIdx.x >> 5, c = threadIdx.x & 31;
    float eg = eAcc, cg = cAcc;
#pragma unroll
    for (int m = 16; m >= 1; m >>= 1) { eg += __shfl_xor(eg, m, 32); cg += __shfl_xor(cg, m, 32); }
    if (c == 0) { sEC[grp * 2] = eg; sEC[grp * 2 + 1] = cg; }
    sP[threadIdx.x] = pAcc;
    __syncthreads();
    float* base = partial + (size_t)level * 34 * PARTW;
    if (threadIdx.x < 32) {
        float ps = 0.f;
#pragma unroll
        for (int r = 0; r < NT / 32; ++r) ps += sP[threadIdx.x + r * 32];
        base[(size_t)(2 + threadIdx.x) * PARTW + col] = ps;
    }
    if (threadIdx.x == 0) {
        float se = 0.f, sc = 0.f;
#pragma unroll
        for (int g = 0; g < NT / 32; ++g) { se += sEC[2 * g]; sc += sEC[2 * g + 1]; }
        base[0 * PARTW + col] = se;
        base[(size_t)1 * PARTW + col] = sc;
    }
}

__device__ __forceinline__ float bsq_eval(float v, float& bit, float& pA, float& eA, float& cA) {
    float sq = v * v;
#pragma unroll
    for (int m = 16; m >= 1; m >>= 1) sq += __shfl_xor(sq, m, 32);
    const float z = v / fmaxf(sqrtf(sq), 1e-12f);
    bit = (z > 0.f) ? 1.0f : 0.0f;
    const float zh = (z > 0.f) ? QSCALE : -QSCALE;
    const float d = zh - z;
    cA += d * d;
    const float p = 1.0f / (1.0f + __expf(ALPHA * z));
    pA += p;
    eA += entf(p) + entf(1.0f - p);
    return zh;
}

// ---------------------------------------------------------------------------
// init: F128[b,m,c] = mean of 64 f rows. Grid B*128.
// ---------------------------------------------------------------------------
__global__ void init_kernel(const float* __restrict__ f, float* __restrict__ F128) {
    const int b = blockIdx.x >> 7, m = blockIdx.x & 127;
    const int c = threadIdx.x & 31, grp = threadIdx.x >> 5;
    const float* fb = f + ((size_t)b * T_DIM + m * 64 + grp * 8) * C_DIM + c;
    float s = 0.f;
#pragma unroll
    for (int i = 0; i < 8; ++i) s += fb[i * C_DIM];
    __shared__ float red[8][32];
    red[grp][c] = s;
    __syncthreads();
    if (grp == 0) {
        float t = red[0][c] + red[1][c] + red[2][c] + red[3][c]
                + red[4][c] + red[5][c] + red[6][c] + red[7][c];
        F128[((size_t)b * 128 + m) * C_DIM + c] = t * (1.0f / 64.0f);
    }
}

// ---------------------------------------------------------------------------
// Levels 0..7 (runtime-loop form): one 1024-thread block per b.
// ---------------------------------------------------------------------------
__global__ __launch_bounds__(1024) void fused_small_kernel(const float* __restrict__ F128,
                                                           float* __restrict__ bits,
                                                           unsigned int* __restrict__ pkG,
                                                           float* __restrict__ partial) {
    const int b = blockIdx.x;
    __shared__ float P[128 * 32];
    __shared__ float qh[127 * 32];
    const int c = threadIdx.x & 31, grp = threadIdx.x >> 5;
    for (int i = threadIdx.x; i < 128 * 32; i += 1024) P[i] = F128[(size_t)b * 128 * 32 + i];
    __syncthreads();
    for (int k = 0; k < 8; ++k) {
        const int pt = 1 << k, W2 = 128 >> k;
        float pAcc = 0.f, eAcc = 0.f, cAcc = 0.f;
        for (int o = grp; o < pt; o += 32) {
            float v = 0.f;
            for (int i = 0; i < W2; ++i) v += P[(o * W2 + i) * 32 + c];
            v *= (1.0f / (float)W2);
            float bit;
            bsq_eval(v, bit, pAcc, eAcc, cAcc);
            bits[((size_t)b * SUM_PT + (pt - 1) + o) * C_DIM + c] = bit;
            const unsigned long long bal = __ballot(bit > 0.5f);
            if (c == 0)
                pkG[(size_t)b * 256 + (pt - 1) + o] =
                    (threadIdx.x & 32) ? (unsigned)(bal >> 32) : (unsigned)bal;
            if (k < 7) qh[((pt - 1) + o) * 32 + c] = bit;
        }
        write_partials<1024>(eAcc, cAcc, pAcc, partial, k, b);
        if (k < 7) {
            __syncthreads();
            for (int m = grp; m < 128; m += 32)
                P[m * 32 + c] -= pooled_up_sum64(&qh[(pt - 1) * 32 + c], 1 << k, m) * (1.0f / 64.0f);
            __syncthreads();
        }
    }
}

// ---------------------------------------------------------------------------
// Levels 8..12 templated level body; bits words kept in a per-level LDS
// pyramid (OFF: 0,10,30,70,150); table-driven midpoint corrections.
// ---------------------------------------------------------------------------
template <int K, int OFF>
__device__ __forceinline__ void cf_level(float* Rl, unsigned int* bitsPyr,
                                         const float* wT, const int* iT,
                                         float* __restrict__ bits,
                                         float* __restrict__ partial, int b,
                                         int L0, int nL, int r0, int r1,
                                         int c, int grp) {
    constexpr int F = 4096 >> K;
    constexpr int ptk = 1 << K;
    const int p0 = L0 / F, pN = nL / F;
    const int own0 = r0 / F, own1 = r1 / F;
    unsigned int* bl = bitsPyr + OFF;
    float pAcc = 0.f, eAcc = 0.f, cAcc = 0.f;
    for (int pl = grp; pl < pN; pl += 16) {
        float v = 0.f;
#pragma unroll
        for (int r = 0; r < F; ++r) v += Rl[(pl * F + r) * 32 + c];
        v *= (1.0f / (float)F);
        float sq = v * v;
#pragma unroll
        for (int m = 16; m >= 1; m >>= 1) sq += __shfl_xor(sq, m, 32);
        const float z = v / fmaxf(sqrtf(sq), 1e-12f);
        const unsigned long long bal = __ballot(z > 0.f);
        const unsigned int word = (threadIdx.x & 32) ? (unsigned)(bal >> 32) : (unsigned)bal;
        if (c == 0) bl[pl] = word;
        const int mg = p0 + pl;
        if (mg >= own0 && mg < own1) {
            bits[((size_t)b * SUM_PT + (ptk - 1) + mg) * C_DIM + c] = (z > 0.f) ? 1.f : 0.f;
            const float zh = (z > 0.f) ? QSCALE : -QSCALE;
            const float d = zh - z;
            cAcc += d * d;
            const float p = 1.0f / (1.0f + __expf(ALPHA * z));
            pAcc += p;
            eAcc += entf(p) + entf(1.0f - p);
        }
    }
    write_partials<512>(eAcc, cAcc, pAcc, partial, K, blockIdx.x);  // entry+mid syncs
    if (K < 12) {
        for (int rl = grp; rl < nL; rl += 16) {
            const float w = wT[rl];
            const int pk = iT[rl];
            const float b0 = (float)((bl[pk & 0xFFFF] >> c) & 1u);
            const float b1 = (float)((bl[pk >> 16] >> c) & 1u);
            Rl[rl * 32 + c] -= ((b0 * (1.0f - w) + b1 * w) * 2.0f - 1.0f) * QSCALE;
        }
        __syncthreads();
    }
}

// ---------------------------------------------------------------------------
// Fused levels 8..12 + level 13. Block = (b, 128-row chunk) = 256 t of output.
// ---------------------------------------------------------------------------
__global__ __launch_bounds__(512) void chunk_final_kernel(const float* __restrict__ f,
                                                          float* __restrict__ outQ,
                                                          float* __restrict__ bits,
                                                          const unsigned int* __restrict__ pkG,
                                                          float* __restrict__ partial) {
    const int b = blockIdx.x >> 5;
    const int chunk = blockIdx.x & 31;
    const int r0 = chunk * OWN, r1 = r0 + OWN;
    const int L0 = max(0, r0 - HALO);
    const int L1 = min(4096, r1 + HALO);
    const int nL = L1 - L0;
    const int nSeg = nL >> 4;
    __shared__ float Rl[MAXL * 32];
    __shared__ unsigned int bitsPyr[310];    // 10+20+40+80+160
    __shared__ unsigned int pk07[255];
    __shared__ float segA[16][32], segB[16][32];
    __shared__ float wT[4 * MAXL];
    __shared__ int iT[4 * MAXL];
    const int c = threadIdx.x & 31, grp = threadIdx.x >> 5;   // 16 groups

    const float* fb = f + ((size_t)b * T_DIM + (size_t)L0 * 2) * C_DIM;
    for (int i = threadIdx.x; i < nL * 8; i += 512) {
        const int row = i >> 3, c4 = i & 7;
        const float4 v0 = *(const float4*)(fb + (size_t)(2 * row) * 32 + c4 * 4);
        const float4 v1 = *(const float4*)(fb + (size_t)(2 * row + 1) * 32 + c4 * 4);
        float4 o;
        o.x = 0.5f * (v0.x + v1.x); o.y = 0.5f * (v0.y + v1.y);
        o.z = 0.5f * (v0.z + v1.z); o.w = 0.5f * (v0.w + v1.w);
        *(float4*)(Rl + row * 32 + c4 * 4) = o;
    }
    for (int i = threadIdx.x; i < 255; i += 512) pk07[i] = pkG[(size_t)b * 256 + i];
    // correction triplet tables for levels 8..11 (bits-independent)
    for (int idx = threadIdx.x; idx < 4 * nL; idx += 512) {
        const int lvl = idx / nL, rl = idx - lvl * nL;
        const int ptk = 256 << lvl;
        const int F = 4096 / ptk;
        const int p0 = L0 / F, pN = nL / F;
        const float a = (float)ptk * (1.0f / (float)T_DIM);
        float pos = (float)(2 * (L0 + rl) + 1) * a - 0.5f;
        pos = fminf(fmaxf(pos, 0.0f), (float)(ptk - 1));
        const int lo = (int)pos;
        const int hi = min(lo + 1, ptk - 1);
        wT[idx] = pos - (float)lo;
        const int lol = min(max(lo - p0, 0), pN - 1);   // clamp only hits don't-care halo
        const int hil = min(max(hi - p0, 0), pN - 1);
        iT[idx] = lol | (hil << 16);
    }
    __syncthreads();

    // j<=7 batch correction: 2 mid-evals per 16-row segment, linear apply.
    for (int w = threadIdx.x; w < nSeg * 32; w += 512) {
        const int s = w >> 5, cc = w & 31;
        const int rg = L0 + s * 16;
        float c0 = 0.f, c1 = 0.f;
#pragma unroll
        for (int j = 0; j < 8; ++j) {
            const int ptj = 1 << j;
            c0 += interp_pk(pk07 + (ptj - 1), ptj, (float)(2 * rg) + 0.5f, cc);
            c1 += interp_pk(pk07 + (ptj - 1), ptj, (float)(2 * rg + 2) + 0.5f, cc);
        }
        segA[s][cc] = c0;
        segB[s][cc] = c1 - c0;
    }
    __syncthreads();
    for (int rl = grp; rl < nL; rl += 16) {
        const int s = rl >> 4;
        Rl[rl * 32 + c] -= fmaf((float)(rl & 15), segB[s][c], segA[s][c]);
    }
    __syncthreads();

    cf_level<8, 0>(Rl, bitsPyr, wT + 0 * nL, iT + 0 * nL, bits, partial, b, L0, nL, r0, r1, c, grp);
    cf_level<9, 10>(Rl, bitsPyr, wT + 1 * nL, iT + 1 * nL, bits, partial, b, L0, nL, r0, r1, c, grp);
    cf_level<10, 30>(Rl, bitsPyr, wT + 2 * nL, iT + 2 * nL, bits, partial, b, L0, nL, r0, r1, c, grp);
    cf_level<11, 70>(Rl, bitsPyr, wT + 3 * nL, iT + 3 * nL, bits, partial, b, L0, nL, r0, r1, c, grp);
    cf_level<12, 150>(Rl, bitsPyr, wT, iT, bits, partial, b, L0, nL, r0, r1, c, grp);

    // ---- level 13 (fused final over this chunk's 256-t window) ----
    __syncthreads();
    const int t0 = 2 * r0;
    const int p8 = L0 / 16, p9 = L0 / 8, p10 = L0 / 4, p11 = L0 / 2, p12 = L0;
    for (int w = threadIdx.x; w < 16 * 32; w += 512) {
        const int s = w >> 5, cc = w & 31;
        const int tA = t0 + s * 16;
        float c0 = 0.f, c1 = 0.f;
#pragma unroll
        for (int j = 0; j < 8; ++j) {
            const int ptj = 1 << j;
            c0 += interp_pk(pk07 + (ptj - 1), ptj, (float)tA, cc);
            c1 += interp_pk(pk07 + (ptj - 1), ptj, (float)(tA + 1), cc);
        }
        c0 += interp_loc<256>(bitsPyr + 0, p8, (float)tA, cc);
        c1 += interp_loc<256>(bitsPyr + 0, p8, (float)(tA + 1), cc);
        segA[s][cc] = c0;
        segB[s][cc] = c1 - c0;
    }
    __syncthreads();
    float pAcc = 0.f, eAcc = 0.f, cAcc = 0.f;
    for (int tt = grp; tt < 2 * OWN; tt += 16) {
        const int t = t0 + tt;
        float up = fmaf((float)(tt & 15), segB[tt >> 4][c], segA[tt >> 4][c]);
        up += interp_loc<512>(bitsPyr + 10, p9, (float)t, c);
        up += interp_loc<1024>(bitsPyr + 30, p10, (float)t, c);
        up += interp_loc<2048>(bitsPyr + 70, p11, (float)t, c);
        up += interp_loc<4096>(bitsPyr + 150, p12, (float)t, c);
        const size_t idx = ((size_t)b * T_DIM + t) * C_DIM + c;
        const float v = f[idx] - up;
        float bit;
        const float zh = bsq_eval(v, bit, pAcc, eAcc, cAcc);
        bits[((size_t)b * SUM_PT + (T_DIM - 1) + t) * C_DIM + c] = bit;
        outQ[idx] = up + zh;
    }
    write_partials<512>(eAcc, cAcc, pAcc, partial, 13, blockIdx.x);
}

// ---------------------------------------------------------------------------
// Merged reduce + finalize: one 1024-thread block.
// ---------------------------------------------------------------------------
__global__ __launch_bounds__(1024) void reduce_finalize(const float* __restrict__ partial,
                                                        float* __restrict__ outL) {
    __shared__ float accS[NLEVEL * 34];
    const int tid = threadIdx.x;
    if (tid < NLEVEL * 34) {
        const int level = tid / 34, comp = tid % 34;
        const int nblk = (level < 8) ? 32 : 1024;
        const float* s = partial + ((size_t)level * 34 + comp) * PARTW;
        float v0 = 0.f, v1 = 0.f, v2 = 0.f, v3 = 0.f;
        for (int i = 0; i < nblk; i += 4) {
            v0 += s[i]; v1 += s[i + 1]; v2 += s[i + 2]; v3 += s[i + 3];
        }
        accS[tid] = (v0 + v1) + (v2 + v3);
    }
    __syncthreads();
    const int k = tid >> 5, c = tid & 31;
    if (k < NLEVEL) {
        const float cnt = (float)(B_DIM << k);
        const float avg_p = accS[k * 34 + 2 + c] / cnt;
        float ec = entf(avg_p) + entf(1.0f - avg_p);
#pragma unroll
        for (int m = 16; m >= 1; m >>= 1) ec += __shfl_xor(ec, m, 32);
        if (c == 0) {
            const float per_sample = accS[k * 34 + 0] / cnt;
            const float commit = accS[k * 34 + 1] / cnt;
            const float pen = (per_sample - ec) * (1.0f / 100.0f);
            outL[k] = pen * 0.1f + commit * 0.2f;
        }
    }
}

extern "C" void kernel_launch(void* const* d_in, const int* in_sizes, int n_in,
                              void* d_out, int out_size, void* d_ws, size_t ws_size,
                              hipStream_t stream) {
    (void)in_sizes; (void)n_in; (void)out_size; (void)ws_size;
    const float* f = (const float*)d_in[0];
    float* outQ = (float*)d_out;                        // N_ELEM floats
    float* outBits = outQ + N_ELEM;                     // BITS_ELEM floats (0.0/1.0)
    float* outL = outBits + BITS_ELEM;                  // 14 floats

    float* partial = (float*)d_ws;                      // 14*34*2048 floats (~3.9MB)
    float* acc = partial + (size_t)NLEVEL * 34 * PARTW; // (layout slot)
    float* F128 = acc + NLEVEL * 64;                    // B*128*C floats (0.5MB)
    unsigned int* pkG = (unsigned int*)(F128 + (size_t)B_DIM * 128 * C_DIM); // B*256 words

    init_kernel<<<B_DIM * 128, 256, 0, stream>>>(f, F128);
    fused_small_kernel<<<B_DIM, 1024, 0, stream>>>(F128, outBits, pkG, partial);
    chunk_final_kernel<<<B_DIM * 32, 512, 0, stream>>>(f, outQ, outBits, pkG, partial);
    reduce_finalize<<<1, 1024, 0, stream>>>(partial, outL);
}

// Round 13
// 182.706 us; speedup vs baseline: 1.0183x; 1.0183x over previous
//
#include <hip/hip_runtime.h>

#define B_DIM 32
#define T_DIM 8192
#define C_DIM 32
#define N_ELEM (B_DIM * T_DIM * C_DIM)      /* 8388608 */
#define SUM_PT 16383
#define BITS_ELEM (B_DIM * SUM_PT * C_DIM)  /* 16776192 */
#define NLEVEL 14
#define PARTW 2048
#define QSCALE 0.17677669529663687f         /* 1/sqrt(32) */
#define ALPHA  70.710678118654755f          /* 4*INV_TEMP/sqrt(32) */

#define OWN 128                              /* 4096-res rows owned per block */
#define HALO 16
#define MAXL (OWN + 2 * HALO)                /* 160 */

__device__ __forceinline__ float entf(float x) { return -(x * __logf(x + 1e-8f)); }
__device__ __forceinline__ float qval(float bit) { return bit * (2.0f * QSCALE) - QSCALE; }

// interp of level-j quant at (possibly half-integer) T-position tpos, packed bit c.
__device__ __forceinline__ float interp_pk(const unsigned int* __restrict__ pkbase,
                                           int ptj, float tpos, int c) {
    const float a = (float)ptj * (1.0f / (float)T_DIM);
    float pos = (tpos + 0.5f) * a - 0.5f;
    pos = fminf(fmaxf(pos, 0.0f), (float)(ptj - 1));
    const int lo = (int)pos;
    const int hi = min(lo + 1, ptj - 1);
    const float w = pos - (float)lo;
    const float b0 = (float)((pkbase[lo] >> c) & 1u);
    const float b1 = (float)((pkbase[hi] >> c) & 1u);
    return ((b0 * (1.0f - w) + b1 * w) * 2.0f - 1.0f) * QSCALE;
}

// interp from a LOCAL packed window (indices proven in-window for owned use).
template <int PTJ>
__device__ __forceinline__ float interp_loc(const unsigned int* __restrict__ bl,
                                            int p0, float tpos, int c) {
    const float a = (float)PTJ * (1.0f / (float)T_DIM);
    float pos = (tpos + 0.5f) * a - 0.5f;
    pos = fminf(fmaxf(pos, 0.0f), (float)(PTJ - 1));
    const int lo = (int)pos;
    const int hi = min(lo + 1, PTJ - 1);
    const float w = pos - (float)lo;
    const float b0 = (float)((bl[lo - p0] >> c) & 1u);
    const float b1 = (float)((bl[hi - p0] >> c) & 1u);
    return ((b0 * (1.0f - w) + b1 * w) * 2.0f - 1.0f) * QSCALE;
}

// Closed-form sum over t in [m*64,(m+1)*64) of float-bits interp, ptj <= 64.
__device__ float pooled_up_sum64(const float* base, int ptj, int m) {
    const int W = 64;
    const float a = (float)ptj * (1.0f / (float)T_DIM);
    const float p0 = ((float)(m * W) + 0.5f) * a - 0.5f;
    const float pmax = (float)(ptj - 1);
    float sum = 0.0f;
    int iL = 0;
    if (p0 < 0.0f) { iL = (int)ceilf(-p0 / a); if (iL > W) iL = W; }
    int iH = W - 1;
    if (p0 + (float)(W - 1) * a > pmax) {
        iH = (int)floorf((pmax - p0) / a);
        if (iH > W - 1) iH = W - 1;
        if (iH < -1) iH = -1;
    }
    if (iL > 0) sum += (float)iL * qval(base[0]);
    if (iH < W - 1) sum += (float)(W - 1 - iH) * qval(base[(size_t)(ptj - 1) * C_DIM]);
    if (iH >= iL) {
        const float pL = p0 + (float)iL * a;
        int l0 = (int)pL;
        if (l0 > ptj - 1) l0 = ptj - 1;
        const int is = (int)ceilf(((float)(l0 + 1) - p0) / a);
        const int endA = min(is - 1, iH);
        if (endA >= iL) {
            const int nA = endA - iL + 1;
            const float sI = 0.5f * (float)(iL + endA) * (float)nA;
            const float SA = (float)nA * (p0 - (float)l0) + a * sI;
            const float q0 = qval(base[(size_t)l0 * C_DIM]);
            const float q1 = qval(base[(size_t)min(l0 + 1, ptj - 1) * C_DIM]);
            sum += (float)nA * q0 + SA * (q1 - q0);
        }
        const int begB = max(is, iL);
        if (begB <= iH) {
            const int nB = iH - begB + 1;
            const float sI = 0.5f * (float)(begB + iH) * (float)nB;
            const float SB = (float)nB * (p0 - (float)(l0 + 1)) + a * sI;
            const float q1 = qval(base[(size_t)min(l0 + 1, ptj - 1) * C_DIM]);
            const float q2 = qval(base[(size_t)min(l0 + 2, ptj - 1) * C_DIM]);
            sum += (float)nB * q1 + SB * (q2 - q1);
        }
    }
    return sum;
}

template <int NT>
__device__ __forceinline__ void write_partials(float eAcc, float cAcc, float pAcc,
                                               float* partial, int level, int col) {
    __shared__ float sP[NT];
    __shared__ float sEC[NT / 16];
    __syncthreads();
    const int grp = threadIdx.x >> 5, c = threadIdx.x & 31;
    float eg = eAcc, cg = cAcc;
#pragma unroll
    for (int m = 16; m >= 1; m >>= 1) { eg += __shfl_xor(eg, m, 32); cg += __shfl_xor(cg, m, 32); }
    if (c == 0) { sEC[grp * 2] = eg; sEC[grp * 2 + 1] = cg; }
    sP[threadIdx.x] = pAcc;
    __syncthreads();
    float* base = partial + (size_t)level * 34 * PARTW;
    if (threadIdx.x < 32) {
        float ps = 0.f;
#pragma unroll
        for (int r = 0; r < NT / 32; ++r) ps += sP[threadIdx.x + r * 32];
        base[(size_t)(2 + threadIdx.x) * PARTW + col] = ps;
    }
    if (threadIdx.x == 0) {
        float se = 0.f, sc = 0.f;
#pragma unroll
        for (int g = 0; g < NT / 32; ++g) { se += sEC[2 * g]; sc += sEC[2 * g + 1]; }
        base[0 * PARTW + col] = se;
        base[(size_t)1 * PARTW + col] = sc;
    }
}

__device__ __forceinline__ float bsq_eval(float v, float& bit, float& pA, float& eA, float& cA) {
    float sq = v * v;
#pragma unroll
    for (int m = 16; m >= 1; m >>= 1) sq += __shfl_xor(sq, m, 32);
    const float z = v / fmaxf(sqrtf(sq), 1e-12f);
    bit = (z > 0.f) ? 1.0f : 0.0f;
    const float zh = (z > 0.f) ? QSCALE : -QSCALE;
    const float d = zh - z;
    cA += d * d;
    const float p = 1.0f / (1.0f + __expf(ALPHA * z));
    pA += p;
    eA += entf(p) + entf(1.0f - p);
    return zh;
}

// ---------------------------------------------------------------------------
// init: F128[b,m,c] = mean of 64 f rows. Grid B*128.
// ---------------------------------------------------------------------------
__global__ void init_kernel(const float* __restrict__ f, float* __restrict__ F128) {
    const int b = blockIdx.x >> 7, m = blockIdx.x & 127;
    const int c = threadIdx.x & 31, grp = threadIdx.x >> 5;
    const float* fb = f + ((size_t)b * T_DIM + m * 64 + grp * 8) * C_DIM + c;
    float s = 0.f;
#pragma unroll
    for (int i = 0; i < 8; ++i) s += fb[i * C_DIM];
    __shared__ float red[8][32];
    red[grp][c] = s;
    __syncthreads();
    if (grp == 0) {
        float t = red[0][c] + red[1][c] + red[2][c] + red[3][c]
                + red[4][c] + red[5][c] + red[6][c] + red[7][c];
        F128[((size_t)b * 128 + m) * C_DIM + c] = t * (1.0f / 64.0f);
    }
}

// ---------------------------------------------------------------------------
// Levels 0..7 (runtime-loop form): one 1024-thread block per b.
// ---------------------------------------------------------------------------
__global__ __launch_bounds__(1024) void fused_small_kernel(const float* __restrict__ F128,
                                                           float* __restrict__ bits,
                                                           unsigned int* __restrict__ pkG,
                                                           float* __restrict__ partial) {
    const int b = blockIdx.x;
    __shared__ float P[128 * 32];
    __shared__ float qh[127 * 32];
    const int c = threadIdx.x & 31, grp = threadIdx.x >> 5;
    for (int i = threadIdx.x; i < 128 * 32; i += 1024) P[i] = F128[(size_t)b * 128 * 32 + i];
    __syncthreads();
    for (int k = 0; k < 8; ++k) {
        const int pt = 1 << k, W2 = 128 >> k;
        float pAcc = 0.f, eAcc = 0.f, cAcc = 0.f;
        for (int o = grp; o < pt; o += 32) {
            float v = 0.f;
            for (int i = 0; i < W2; ++i) v += P[(o * W2 + i) * 32 + c];
            v *= (1.0f / (float)W2);
            float bit;
            bsq_eval(v, bit, pAcc, eAcc, cAcc);
            bits[((size_t)b * SUM_PT + (pt - 1) + o) * C_DIM + c] = bit;
            const unsigned long long bal = __ballot(bit > 0.5f);
            if (c == 0)
                pkG[(size_t)b * 256 + (pt - 1) + o] =
                    (threadIdx.x & 32) ? (unsigned)(bal >> 32) : (unsigned)bal;
            if (k < 7) qh[((pt - 1) + o) * 32 + c] = bit;
        }
        write_partials<1024>(eAcc, cAcc, pAcc, partial, k, b);
        if (k < 7) {
            __syncthreads();
            for (int m = grp; m < 128; m += 32)
                P[m * 32 + c] -= pooled_up_sum64(&qh[(pt - 1) * 32 + c], 1 << k, m) * (1.0f / 64.0f);
            __syncthreads();
        }
    }
}

// ---------------------------------------------------------------------------
// Levels 8..12 templated level body; bits words kept in a per-level LDS
// pyramid (OFF: 0,10,30,70,150); table-driven midpoint corrections.
// ---------------------------------------------------------------------------
template <int K, int OFF>
__device__ __forceinline__ void cf_level(float* Rl, unsigned int* bitsPyr,
                                         const float* wT, const int* iT,
                                         float* __restrict__ bits,
                                         float* __restrict__ partial, int b,
                                         int L0, int nL, int r0, int r1,
                                         int c, int grp) {
    constexpr int F = 4096 >> K;
    constexpr int ptk = 1 << K;
    const int p0 = L0 / F, pN = nL / F;
    const int own0 = r0 / F, own1 = r1 / F;
    unsigned int* bl = bitsPyr + OFF;
    float pAcc = 0.f, eAcc = 0.f, cAcc = 0.f;
    for (int pl = grp; pl < pN; pl += 16) {
        float v = 0.f;
#pragma unroll
        for (int r = 0; r < F; ++r) v += Rl[(pl * F + r) * 32 + c];
        v *= (1.0f / (float)F);
        float sq = v * v;
#pragma unroll
        for (int m = 16; m >= 1; m >>= 1) sq += __shfl_xor(sq, m, 32);
        const float z = v / fmaxf(sqrtf(sq), 1e-12f);
        const unsigned long long bal = __ballot(z > 0.f);
        const unsigned int word = (threadIdx.x & 32) ? (unsigned)(bal >> 32) : (unsigned)bal;
        if (c == 0) bl[pl] = word;
        const int mg = p0 + pl;
        if (mg >= own0 && mg < own1) {
            bits[((size_t)b * SUM_PT + (ptk - 1) + mg) * C_DIM + c] = (z > 0.f) ? 1.f : 0.f;
            const float zh = (z > 0.f) ? QSCALE : -QSCALE;
            const float d = zh - z;
            cAcc += d * d;
            const float p = 1.0f / (1.0f + __expf(ALPHA * z));
            pAcc += p;
            eAcc += entf(p) + entf(1.0f - p);
        }
    }
    write_partials<512>(eAcc, cAcc, pAcc, partial, K, blockIdx.x);  // entry+mid syncs
    if (K < 12) {
        for (int rl = grp; rl < nL; rl += 16) {
            const float w = wT[rl];
            const int pk = iT[rl];
            const float b0 = (float)((bl[pk & 0xFFFF] >> c) & 1u);
            const float b1 = (float)((bl[pk >> 16] >> c) & 1u);
            Rl[rl * 32 + c] -= ((b0 * (1.0f - w) + b1 * w) * 2.0f - 1.0f) * QSCALE;
        }
        __syncthreads();
    }
}

// ---------------------------------------------------------------------------
// Fused levels 8..12 + level 13. Block = (b, 128-row chunk) = 256 t of output.
// Level-13 main loop processes t-PAIRS: levels 9..11 share (lo,hi) within a
// pair (knot-parity proof), level 12 uses 3 words/pair. (lo,w) derived with
// integer ops on exact dyadics -> bit-identical to the float-pos path.
// ---------------------------------------------------------------------------
__global__ __launch_bounds__(512) void chunk_final_kernel(const float* __restrict__ f,
                                                          float* __restrict__ outQ,
                                                          float* __restrict__ bits,
                                                          const unsigned int* __restrict__ pkG,
                                                          float* __restrict__ partial) {
    const int b = blockIdx.x >> 5;
    const int chunk = blockIdx.x & 31;
    const int r0 = chunk * OWN, r1 = r0 + OWN;
    const int L0 = max(0, r0 - HALO);
    const int L1 = min(4096, r1 + HALO);
    const int nL = L1 - L0;
    const int nSeg = nL >> 4;
    __shared__ float Rl[MAXL * 32];
    __shared__ unsigned int bitsPyr[310];    // 10+20+40+80+160
    __shared__ unsigned int pk07[255];
    __shared__ float segA[16][32], segB[16][32];
    __shared__ float wT[4 * MAXL];
    __shared__ int iT[4 * MAXL];
    const int c = threadIdx.x & 31, grp = threadIdx.x >> 5;   // 16 groups

    const float* fb = f + ((size_t)b * T_DIM + (size_t)L0 * 2) * C_DIM;
    for (int i = threadIdx.x; i < nL * 8; i += 512) {
        const int row = i >> 3, c4 = i & 7;
        const float4 v0 = *(const float4*)(fb + (size_t)(2 * row) * 32 + c4 * 4);
        const float4 v1 = *(const float4*)(fb + (size_t)(2 * row + 1) * 32 + c4 * 4);
        float4 o;
        o.x = 0.5f * (v0.x + v1.x); o.y = 0.5f * (v0.y + v1.y);
        o.z = 0.5f * (v0.z + v1.z); o.w = 0.5f * (v0.w + v1.w);
        *(float4*)(Rl + row * 32 + c4 * 4) = o;
    }
    for (int i = threadIdx.x; i < 255; i += 512) pk07[i] = pkG[(size_t)b * 256 + i];
    // correction triplet tables for levels 8..11 (bits-independent)
    for (int idx = threadIdx.x; idx < 4 * nL; idx += 512) {
        const int lvl = idx / nL, rl = idx - lvl * nL;
        const int ptk = 256 << lvl;
        const int F = 4096 / ptk;
        const int p0 = L0 / F, pN = nL / F;
        const float a = (float)ptk * (1.0f / (float)T_DIM);
        float pos = (float)(2 * (L0 + rl) + 1) * a - 0.5f;
        pos = fminf(fmaxf(pos, 0.0f), (float)(ptk - 1));
        const int lo = (int)pos;
        const int hi = min(lo + 1, ptk - 1);
        wT[idx] = pos - (float)lo;
        const int lol = min(max(lo - p0, 0), pN - 1);   // clamp only hits don't-care halo
        const int hil = min(max(hi - p0, 0), pN - 1);
        iT[idx] = lol | (hil << 16);
    }
    __syncthreads();

    // j<=7 batch correction: 2 mid-evals per 16-row segment, linear apply.
    for (int w = threadIdx.x; w < nSeg * 32; w += 512) {
        const int s = w >> 5, cc = w & 31;
        const int rg = L0 + s * 16;
        float c0 = 0.f, c1 = 0.f;
#pragma unroll
        for (int j = 0; j < 8; ++j) {
            const int ptj = 1 << j;
            c0 += interp_pk(pk07 + (ptj - 1), ptj, (float)(2 * rg) + 0.5f, cc);
            c1 += interp_pk(pk07 + (ptj - 1), ptj, (float)(2 * rg + 2) + 0.5f, cc);
        }
        segA[s][cc] = c0;
        segB[s][cc] = c1 - c0;
    }
    __syncthreads();
    for (int rl = grp; rl < nL; rl += 16) {
        const int s = rl >> 4;
        Rl[rl * 32 + c] -= fmaf((float)(rl & 15), segB[s][c], segA[s][c]);
    }
    __syncthreads();

    cf_level<8, 0>(Rl, bitsPyr, wT + 0 * nL, iT + 0 * nL, bits, partial, b, L0, nL, r0, r1, c, grp);
    cf_level<9, 10>(Rl, bitsPyr, wT + 1 * nL, iT + 1 * nL, bits, partial, b, L0, nL, r0, r1, c, grp);
    cf_level<10, 30>(Rl, bitsPyr, wT + 2 * nL, iT + 2 * nL, bits, partial, b, L0, nL, r0, r1, c, grp);
    cf_level<11, 70>(Rl, bitsPyr, wT + 3 * nL, iT + 3 * nL, bits, partial, b, L0, nL, r0, r1, c, grp);
    cf_level<12, 150>(Rl, bitsPyr, wT, iT, bits, partial, b, L0, nL, r0, r1, c, grp);

    // ---- level 13 (fused final over this chunk's 256-t window) ----
    __syncthreads();
    const int t0 = 2 * r0;
    const int p8 = L0 / 16, p9 = L0 / 8, p10 = L0 / 4, p11 = L0 / 2;
    for (int w = threadIdx.x; w < 16 * 32; w += 512) {
        const int s = w >> 5, cc = w & 31;
        const int tA = t0 + s * 16;
        float c0 = 0.f, c1 = 0.f;
#pragma unroll
        for (int j = 0; j < 8; ++j) {
            const int ptj = 1 << j;
            c0 += interp_pk(pk07 + (ptj - 1), ptj, (float)tA, cc);
            c1 += interp_pk(pk07 + (ptj - 1), ptj, (float)(tA + 1), cc);
        }
        c0 += interp_loc<256>(bitsPyr + 0, p8, (float)tA, cc);
        c1 += interp_loc<256>(bitsPyr + 0, p8, (float)(tA + 1), cc);
        segA[s][cc] = c0;
        segB[s][cc] = c1 - c0;
    }
    __syncthreads();
    const unsigned int* bl9 = bitsPyr + 10;
    const unsigned int* bl10 = bitsPyr + 30;
    const unsigned int* bl11 = bitsPyr + 70;
    const unsigned int* bl12 = bitsPyr + 150;
    float pAcc = 0.f, eAcc = 0.f, cAcc = 0.f;
    for (int j2 = grp; j2 < OWN; j2 += 16) {          // pair index
        const int mg = r0 + j2;                        // global 4096-row
        const int lr = mg - L0;                        // local row
        const int te = 2 * mg;                         // even t (global)
        const int tte = 2 * j2;                        // even t (local)
        const int s = tte >> 4;

        // ---- level 9 (PTJ=512): shared lo/hi, w pattern ----
        const int e9 = te & 15;                        // even
        int lo9 = (te >> 4) - 1 + (e9 >= 8 ? 1 : 0);
        float w9e = (e9 < 8 ? (float)(17 + 2 * e9) : (float)(2 * e9 - 15)) * (1.0f / 32.0f);
        float w9o = w9e + (1.0f / 16.0f);
        if (lo9 < 0) { lo9 = 0; w9e = 0.f; w9o = 0.f; }
        const int hi9 = min(lo9 + 1, 511);
        const float b9a = (float)((bl9[lo9 - p9] >> c) & 1u);
        const float b9b = (float)((bl9[hi9 - p9] >> c) & 1u);

        // ---- level 10 (PTJ=1024) ----
        const int e10 = te & 7;
        int lo10 = (te >> 3) - 1 + (e10 >= 4 ? 1 : 0);
        float w10e = (e10 < 4 ? (float)(9 + 2 * e10) : (float)(2 * e10 - 7)) * (1.0f / 16.0f);
        float w10o = w10e + (1.0f / 8.0f);
        if (lo10 < 0) { lo10 = 0; w10e = 0.f; w10o = 0.f; }
        const int hi10 = min(lo10 + 1, 1023);
        const float b10a = (float)((bl10[lo10 - p10] >> c) & 1u);
        const float b10b = (float)((bl10[hi10 - p10] >> c) & 1u);

        // ---- level 11 (PTJ=2048) ----
        const int e11 = te & 3;
        int lo11 = (te >> 2) - 1 + (e11 >= 2 ? 1 : 0);
        float w11e = (e11 < 2 ? (float)(5 + 2 * e11) : (float)(2 * e11 - 3)) * (1.0f / 8.0f);
        float w11o = w11e + (1.0f / 4.0f);
        if (lo11 < 0) { lo11 = 0; w11e = 0.f; w11o = 0.f; }
        const int hi11 = min(lo11 + 1, 2047);
        const float b11a = (float)((bl11[lo11 - p11] >> c) & 1u);
        const float b11b = (float)((bl11[hi11 - p11] >> c) & 1u);

        // ---- level 12 (PTJ=4096): 3 words for the pair ----
        const float q12m1 = (float)((bl12[max(lr - 1, 0)] >> c) & 1u);
        const float q12z = (float)((bl12[lr] >> c) & 1u);
        const float q12p1 = (float)((bl12[min(lr + 1, nL - 1)] >> c) & 1u);
        const float w12e = (mg == 0) ? 0.f : 0.75f;
        const float w12o = 0.25f;

        // ---- assemble up for even/odd (same value expr + add order as before) ----
        float upe = fmaf((float)(tte & 15), segB[s][c], segA[s][c]);
        upe += ((b9a * (1.0f - w9e) + b9b * w9e) * 2.0f - 1.0f) * QSCALE;
        upe += ((b10a * (1.0f - w10e) + b10b * w10e) * 2.0f - 1.0f) * QSCALE;
        upe += ((b11a * (1.0f - w11e) + b11b * w11e) * 2.0f - 1.0f) * QSCALE;
        upe += ((q12m1 * (1.0f - w12e) + q12z * w12e) * 2.0f - 1.0f) * QSCALE;

        float upo = fmaf((float)((tte + 1) & 15), segB[s][c], segA[s][c]);
        upo += ((b9a * (1.0f - w9o) + b9b * w9o) * 2.0f - 1.0f) * QSCALE;
        upo += ((b10a * (1.0f - w10o) + b10b * w10o) * 2.0f - 1.0f) * QSCALE;
        upo += ((b11a * (1.0f - w11o) + b11b * w11o) * 2.0f - 1.0f) * QSCALE;
        upo += ((q12z * (1.0f - w12o) + q12p1 * w12o) * 2.0f - 1.0f) * QSCALE;

        // ---- even element ----
        {
            const size_t idx = ((size_t)b * T_DIM + te) * C_DIM + c;
            const float v = f[idx] - upe;
            float bit;
            const float zh = bsq_eval(v, bit, pAcc, eAcc, cAcc);
            bits[((size_t)b * SUM_PT + (T_DIM - 1) + te) * C_DIM + c] = bit;
            outQ[idx] = upe + zh;
        }
        // ---- odd element ----
        {
            const size_t idx = ((size_t)b * T_DIM + te + 1) * C_DIM + c;
            const float v = f[idx] - upo;
            float bit;
            const float zh = bsq_eval(v, bit, pAcc, eAcc, cAcc);
            bits[((size_t)b * SUM_PT + (T_DIM - 1) + te + 1) * C_DIM + c] = bit;
            outQ[idx] = upo + zh;
        }
    }
    write_partials<512>(eAcc, cAcc, pAcc, partial, 13, blockIdx.x);
}

// ---------------------------------------------------------------------------
// Merged reduce + finalize: one 1024-thread block.
// ---------------------------------------------------------------------------
__global__ __launch_bounds__(1024) void reduce_finalize(const float* __restrict__ partial,
                                                        float* __restrict__ outL) {
    __shared__ float accS[NLEVEL * 34];
    const int tid = threadIdx.x;
    if (tid < NLEVEL * 34) {
        const int level = tid / 34, comp = tid % 34;
        const int nblk = (level < 8) ? 32 : 1024;
        const float* s = partial + ((size_t)level * 34 + comp) * PARTW;
        float v0 = 0.f, v1 = 0.f, v2 = 0.f, v3 = 0.f;
        for (int i = 0; i < nblk; i += 4) {
            v0 += s[i]; v1 += s[i + 1]; v2 += s[i + 2]; v3 += s[i + 3];
        }
        accS[tid] = (v0 + v1) + (v2 + v3);
    }
    __syncthreads();
    const int k = tid >> 5, c = tid & 31;
    if (k < NLEVEL) {
        const float cnt = (float)(B_DIM << k);
        const float avg_p = accS[k * 34 + 2 + c] / cnt;
        float ec = entf(avg_p) + entf(1.0f - avg_p);
#pragma unroll
        for (int m = 16; m >= 1; m >>= 1) ec += __shfl_xor(ec, m, 32);
        if (c == 0) {
            const float per_sample = accS[k * 34 + 0] / cnt;
            const float commit = accS[k * 34 + 1] / cnt;
            const float pen = (per_sample - ec) * (1.0f / 100.0f);
            outL[k] = pen * 0.1f + commit * 0.2f;
        }
    }
}

extern "C" void kernel_launch(void* const* d_in, const int* in_sizes, int n_in,
                              void* d_out, int out_size, void* d_ws, size_t ws_size,
                              hipStream_t stream) {
    (void)in_sizes; (void)n_in; (void)out_size; (void)ws_size;
    const float* f = (const float*)d_in[0];
    float* outQ = (float*)d_out;                        // N_ELEM floats
    float* outBits = outQ + N_ELEM;                     // BITS_ELEM floats (0.0/1.0)
    float* outL = outBits + BITS_ELEM;                  // 14 floats

    float* partial = (float*)d_ws;                      // 14*34*2048 floats (~3.9MB)
    float* acc = partial + (size_t)NLEVEL * 34 * PARTW; // (layout slot)
    float* F128 = acc + NLEVEL * 64;                    // B*128*C floats (0.5MB)
    unsigned int* pkG = (unsigned int*)(F128 + (size_t)B_DIM * 128 * C_DIM); // B*256 words

    init_kernel<<<B_DIM * 128, 256, 0, stream>>>(f, F128);
    fused_small_kernel<<<B_DIM, 1024, 0, stream>>>(F128, outBits, pkG, partial);
    chunk_final_kernel<<<B_DIM * 32, 512, 0, stream>>>(f, outQ, outBits, pkG, partial);
    reduce_finalize<<<1, 1024, 0, stream>>>(partial, outL);
}

// Round 14
// 173.919 us; speedup vs baseline: 1.0698x; 1.0505x over previous
//
#include <hip/hip_runtime.h>

#define B_DIM 32
#define T_DIM 8192
#define C_DIM 32
#define N_ELEM (B_DIM * T_DIM * C_DIM)      /* 8388608 */
#define SUM_PT 16383
#define BITS_ELEM (B_DIM * SUM_PT * C_DIM)  /* 16776192 */
#define NLEVEL 14
#define PARTB 8192                           /* chunk partial cols: 1024 blk * 8 waves */
#define PARTS 512                            /* small partial cols: 32 blk * 16 waves */
#define QSCALE 0.17677669529663687f         /* 1/sqrt(32) */
#define ALPHA  70.710678118654755f          /* 4*INV_TEMP/sqrt(32) */

#define OWN 128                              /* 4096-res rows owned per block */
#define HALO 16
#define MAXL (OWN + 2 * HALO)                /* 160 */

__device__ __forceinline__ float entf(float x) { return -(x * __logf(x + 1e-8f)); }
__device__ __forceinline__ float qval(float bit) { return bit * (2.0f * QSCALE) - QSCALE; }

// interp of level-j quant at (possibly half-integer) T-position tpos, packed bit c.
__device__ __forceinline__ float interp_pk(const unsigned int* __restrict__ pkbase,
                                           int ptj, float tpos, int c) {
    const float a = (float)ptj * (1.0f / (float)T_DIM);
    float pos = (tpos + 0.5f) * a - 0.5f;
    pos = fminf(fmaxf(pos, 0.0f), (float)(ptj - 1));
    const int lo = (int)pos;
    const int hi = min(lo + 1, ptj - 1);
    const float w = pos - (float)lo;
    const float b0 = (float)((pkbase[lo] >> c) & 1u);
    const float b1 = (float)((pkbase[hi] >> c) & 1u);
    return ((b0 * (1.0f - w) + b1 * w) * 2.0f - 1.0f) * QSCALE;
}

// interp from a LOCAL packed window (indices proven in-window for owned use).
template <int PTJ>
__device__ __forceinline__ float interp_loc(const unsigned int* __restrict__ bl,
                                            int p0, float tpos, int c) {
    const float a = (float)PTJ * (1.0f / (float)T_DIM);
    float pos = (tpos + 0.5f) * a - 0.5f;
    pos = fminf(fmaxf(pos, 0.0f), (float)(PTJ - 1));
    const int lo = (int)pos;
    const int hi = min(lo + 1, PTJ - 1);
    const float w = pos - (float)lo;
    const float b0 = (float)((bl[lo - p0] >> c) & 1u);
    const float b1 = (float)((bl[hi - p0] >> c) & 1u);
    return ((b0 * (1.0f - w) + b1 * w) * 2.0f - 1.0f) * QSCALE;
}

// table-driven interp value from packed LDS words
__device__ __forceinline__ float evalT(const unsigned int* __restrict__ bl,
                                       float w, int pk, int c) {
    const float b0 = (float)((bl[pk & 0xFFFF] >> c) & 1u);
    const float b1 = (float)((bl[pk >> 16] >> c) & 1u);
    return ((b0 * (1.0f - w) + b1 * w) * 2.0f - 1.0f) * QSCALE;
}

// Closed-form sum over t in [m*64,(m+1)*64) of float-bits interp, ptj <= 64.
__device__ float pooled_up_sum64(const float* base, int ptj, int m) {
    const int W = 64;
    const float a = (float)ptj * (1.0f / (float)T_DIM);
    const float p0 = ((float)(m * W) + 0.5f) * a - 0.5f;
    const float pmax = (float)(ptj - 1);
    float sum = 0.0f;
    int iL = 0;
    if (p0 < 0.0f) { iL = (int)ceilf(-p0 / a); if (iL > W) iL = W; }
    int iH = W - 1;
    if (p0 + (float)(W - 1) * a > pmax) {
        iH = (int)floorf((pmax - p0) / a);
        if (iH > W - 1) iH = W - 1;
        if (iH < -1) iH = -1;
    }
    if (iL > 0) sum += (float)iL * qval(base[0]);
    if (iH < W - 1) sum += (float)(W - 1 - iH) * qval(base[(size_t)(ptj - 1) * C_DIM]);
    if (iH >= iL) {
        const float pL = p0 + (float)iL * a;
        int l0 = (int)pL;
        if (l0 > ptj - 1) l0 = ptj - 1;
        const int is = (int)ceilf(((float)(l0 + 1) - p0) / a);
        const int endA = min(is - 1, iH);
        if (endA >= iL) {
            const int nA = endA - iL + 1;
            const float sI = 0.5f * (float)(iL + endA) * (float)nA;
            const float SA = (float)nA * (p0 - (float)l0) + a * sI;
            const float q0 = qval(base[(size_t)l0 * C_DIM]);
            const float q1 = qval(base[(size_t)min(l0 + 1, ptj - 1) * C_DIM]);
            sum += (float)nA * q0 + SA * (q1 - q0);
        }
        const int begB = max(is, iL);
        if (begB <= iH) {
            const int nB = iH - begB + 1;
            const float sI = 0.5f * (float)(begB + iH) * (float)nB;
            const float SB = (float)nB * (p0 - (float)(l0 + 1)) + a * sI;
            const float q1 = qval(base[(size_t)min(l0 + 1, ptj - 1) * C_DIM]);
            const float q2 = qval(base[(size_t)min(l0 + 2, ptj - 1) * C_DIM]);
            sum += (float)nB * q1 + SB * (q2 - q1);
        }
    }
    return sum;
}

// Per-WAVE partial write: NO barrier, no LDS. base = partial slice for level.
// e/c summed over 64 lanes; p summed over lane pairs (c, c+32) -> per channel.
__device__ __forceinline__ void wave_partials(float e, float cm, float p,
                                              float* base, int stride, int col) {
    float eg = e, cg = cm;
#pragma unroll
    for (int m = 32; m >= 1; m >>= 1) { eg += __shfl_xor(eg, m, 64); cg += __shfl_xor(cg, m, 64); }
    const float p2 = p + __shfl_xor(p, 32, 64);
    const int lane = threadIdx.x & 63;
    if (lane < 32) base[(size_t)(2 + lane) * stride + col] = p2;
    if (lane == 0) { base[col] = eg; base[(size_t)stride + col] = cg; }
}

__device__ __forceinline__ float bsq_eval(float v, float& bit, float& pA, float& eA, float& cA) {
    float sq = v * v;
#pragma unroll
    for (int m = 16; m >= 1; m >>= 1) sq += __shfl_xor(sq, m, 32);
    const float z = v / fmaxf(sqrtf(sq), 1e-12f);
    bit = (z > 0.f) ? 1.0f : 0.0f;
    const float zh = (z > 0.f) ? QSCALE : -QSCALE;
    const float d = zh - z;
    cA += d * d;
    const float p = 1.0f / (1.0f + __expf(ALPHA * z));
    pA += p;
    eA += entf(p) + entf(1.0f - p);
    return zh;
}

// ---------------------------------------------------------------------------
// init: F128[b,m,c] = mean of 64 f rows. Grid B*128.
// ---------------------------------------------------------------------------
__global__ void init_kernel(const float* __restrict__ f, float* __restrict__ F128) {
    const int b = blockIdx.x >> 7, m = blockIdx.x & 127;
    const int c = threadIdx.x & 31, grp = threadIdx.x >> 5;
    const float* fb = f + ((size_t)b * T_DIM + m * 64 + grp * 8) * C_DIM + c;
    float s = 0.f;
#pragma unroll
    for (int i = 0; i < 8; ++i) s += fb[i * C_DIM];
    __shared__ float red[8][32];
    red[grp][c] = s;
    __syncthreads();
    if (grp == 0) {
        float t = red[0][c] + red[1][c] + red[2][c] + red[3][c]
                + red[4][c] + red[5][c] + red[6][c] + red[7][c];
        F128[((size_t)b * 128 + m) * C_DIM + c] = t * (1.0f / 64.0f);
    }
}

// ---------------------------------------------------------------------------
// Levels 0..7: one 1024-thread block per b; wave-local partials (2 barriers/level).
// ---------------------------------------------------------------------------
__global__ __launch_bounds__(1024) void fused_small_kernel(const float* __restrict__ F128,
                                                           float* __restrict__ bits,
                                                           unsigned int* __restrict__ pkG,
                                                           float* __restrict__ pSm) {
    const int b = blockIdx.x;
    __shared__ float P[128 * 32];
    __shared__ float qh[127 * 32];
    const int c = threadIdx.x & 31, grp = threadIdx.x >> 5;
    const int col = b * 16 + (threadIdx.x >> 6);
    for (int i = threadIdx.x; i < 128 * 32; i += 1024) P[i] = F128[(size_t)b * 128 * 32 + i];
    __syncthreads();
    for (int k = 0; k < 8; ++k) {
        const int pt = 1 << k, W2 = 128 >> k;
        float pAcc = 0.f, eAcc = 0.f, cAcc = 0.f;
        for (int o = grp; o < pt; o += 32) {
            float v = 0.f;
            for (int i = 0; i < W2; ++i) v += P[(o * W2 + i) * 32 + c];
            v *= (1.0f / (float)W2);
            float bit;
            bsq_eval(v, bit, pAcc, eAcc, cAcc);
            bits[((size_t)b * SUM_PT + (pt - 1) + o) * C_DIM + c] = bit;
            const unsigned long long bal = __ballot(bit > 0.5f);
            if (c == 0)
                pkG[(size_t)b * 256 + (pt - 1) + o] =
                    (threadIdx.x & 32) ? (unsigned)(bal >> 32) : (unsigned)bal;
            if (k < 7) qh[((pt - 1) + o) * 32 + c] = bit;
        }
        wave_partials(eAcc, cAcc, pAcc, pSm + (size_t)k * 34 * PARTS, PARTS, col);
        if (k < 7) {
            __syncthreads();
            for (int m = grp; m < 128; m += 32)
                P[m * 32 + c] -= pooled_up_sum64(&qh[(pt - 1) * 32 + c], 1 << k, m) * (1.0f / 64.0f);
            __syncthreads();
        }
    }
}

// ---------------------------------------------------------------------------
// Table builder: eval triplets of level-J up at centers of level-K windows.
// ---------------------------------------------------------------------------
template <int K, int J, int TO>
__device__ __forceinline__ void buildTab(float* tw, int* ti, int L0, int nL) {
    constexpr int FK = 4096 >> K;
    constexpr int ptj = 1 << J;
    constexpr int FJ = 4096 >> J;
    const int pN = nL / FK;
    const int p0j = L0 / FJ;
    const int pNj = nL / FJ;
    for (int pl = threadIdx.x; pl < pN; pl += 512) {
        const float tpos = (float)(2 * (L0 + pl * FK) + FK) - 0.5f;
        const float a = (float)ptj * (1.0f / (float)T_DIM);
        float pos = (tpos + 0.5f) * a - 0.5f;
        pos = fminf(fmaxf(pos, 0.0f), (float)(ptj - 1));
        const int lo = (int)pos;
        const int hi = min(lo + 1, ptj - 1);
        tw[TO + pl] = pos - (float)lo;
        const int lol = min(max(lo - p0j, 0), pNj - 1);   // clamp only hits don't-care halo
        const int hil = min(max(hi - p0j, 0), pNj - 1);
        ti[TO + pl] = lol | (hil << 16);
    }
}

// ---------------------------------------------------------------------------
// Levels 8..12 level body, CORRECTION-FREE: pooled value = sum(Rl)/F minus
// table-driven evals of all prior levels at the window center. Rl is never
// modified. Exactly ONE barrier per level (publish bl words).
// ---------------------------------------------------------------------------
template <int K>
__device__ __forceinline__ void cf_level(const float* Rl, unsigned int* bitsPyr,
                                         const float* tw, const int* ti,
                                         float* __restrict__ bits,
                                         float* __restrict__ pBig,
                                         int b, int L0, int nL, int r0, int r1,
                                         int c, int grp, int col) {
    constexpr int F = 4096 >> K;
    constexpr int ptk = 1 << K;
    constexpr int OFF = (K == 8) ? 0 : (K == 9) ? 10 : (K == 10) ? 30 : (K == 11) ? 70 : 150;
    constexpr int TB8 = (K == 9) ? 0 : (K == 10) ? 20 : (K == 11) ? 100 : 340;
    constexpr int TB9 = (K == 10) ? 60 : (K == 11) ? 180 : 500;
    constexpr int TB10 = (K == 11) ? 260 : 660;
    constexpr int TB11 = 820;
    const int p0 = L0 / F, pN = nL / F;
    const int own0 = r0 / F, own1 = r1 / F;
    unsigned int* bl = bitsPyr + OFF;
    float pAcc = 0.f, eAcc = 0.f, cAcc = 0.f;
    for (int pl = grp; pl < pN; pl += 16) {
        float v = 0.f;
#pragma unroll
        for (int r = 0; r < F; ++r) v += Rl[(pl * F + r) * 32 + c];
        v *= (1.0f / (float)F);
        if (K >= 9)  v -= evalT(bitsPyr + 0,  tw[TB8 + pl],  ti[TB8 + pl], c);
        if (K >= 10) v -= evalT(bitsPyr + 10, tw[TB9 + pl],  ti[TB9 + pl], c);
        if (K >= 11) v -= evalT(bitsPyr + 30, tw[TB10 + pl], ti[TB10 + pl], c);
        if (K >= 12) v -= evalT(bitsPyr + 70, tw[TB11 + pl], ti[TB11 + pl], c);
        float sq = v * v;
#pragma unroll
        for (int m = 16; m >= 1; m >>= 1) sq += __shfl_xor(sq, m, 32);
        const float z = v / fmaxf(sqrtf(sq), 1e-12f);
        const unsigned long long bal = __ballot(z > 0.f);
        const unsigned int word = (threadIdx.x & 32) ? (unsigned)(bal >> 32) : (unsigned)bal;
        if (c == 0) bl[pl] = word;
        const int mg = p0 + pl;
        if (mg >= own0 && mg < own1) {
            bits[((size_t)b * SUM_PT + (ptk - 1) + mg) * C_DIM + c] = (z > 0.f) ? 1.f : 0.f;
            const float zh = (z > 0.f) ? QSCALE : -QSCALE;
            const float d = zh - z;
            cAcc += d * d;
            const float p = 1.0f / (1.0f + __expf(ALPHA * z));
            pAcc += p;
            eAcc += entf(p) + entf(1.0f - p);
        }
    }
    wave_partials(eAcc, cAcc, pAcc, pBig + (size_t)(K - 8) * 34 * PARTB, PARTB, col);
    __syncthreads();   // publish bl words for next level / level 13
}

// ---------------------------------------------------------------------------
// Fused levels 8..12 + level 13. Block = (b, 128-row chunk) = 256 t of output.
// ---------------------------------------------------------------------------
__global__ __launch_bounds__(512) void chunk_final_kernel(const float* __restrict__ f,
                                                          float* __restrict__ outQ,
                                                          float* __restrict__ bits,
                                                          const unsigned int* __restrict__ pkG,
                                                          float* __restrict__ pBig) {
    const int b = blockIdx.x >> 5;
    const int chunk = blockIdx.x & 31;
    const int r0 = chunk * OWN, r1 = r0 + OWN;
    const int L0 = max(0, r0 - HALO);
    const int L1 = min(4096, r1 + HALO);
    const int nL = L1 - L0;
    const int nSeg = nL >> 4;
    __shared__ float Rl[MAXL * 32];
    __shared__ unsigned int bitsPyr[310];    // 10+20+40+80+160
    __shared__ unsigned int pk07[255];
    __shared__ float segA[16][32], segB[16][32];
    __shared__ float tw[980];
    __shared__ int ti[980];
    const int c = threadIdx.x & 31, grp = threadIdx.x >> 5;   // 16 groups
    const int col = blockIdx.x * 8 + (threadIdx.x >> 6);      // 8 waves

    const float* fb = f + ((size_t)b * T_DIM + (size_t)L0 * 2) * C_DIM;
    for (int i = threadIdx.x; i < nL * 8; i += 512) {
        const int row = i >> 3, c4 = i & 7;
        const float4 v0 = *(const float4*)(fb + (size_t)(2 * row) * 32 + c4 * 4);
        const float4 v1 = *(const float4*)(fb + (size_t)(2 * row + 1) * 32 + c4 * 4);
        float4 o;
        o.x = 0.5f * (v0.x + v1.x); o.y = 0.5f * (v0.y + v1.y);
        o.z = 0.5f * (v0.z + v1.z); o.w = 0.5f * (v0.w + v1.w);
        *(float4*)(Rl + row * 32 + c4 * 4) = o;
    }
    for (int i = threadIdx.x; i < 255; i += 512) pk07[i] = pkG[(size_t)b * 256 + i];
    // eval tables: (K, J) pairs at level-K window centers (bits-independent)
    buildTab<9, 8, 0>(tw, ti, L0, nL);
    buildTab<10, 8, 20>(tw, ti, L0, nL);
    buildTab<10, 9, 60>(tw, ti, L0, nL);
    buildTab<11, 8, 100>(tw, ti, L0, nL);
    buildTab<11, 9, 180>(tw, ti, L0, nL);
    buildTab<11, 10, 260>(tw, ti, L0, nL);
    buildTab<12, 8, 340>(tw, ti, L0, nL);
    buildTab<12, 9, 500>(tw, ti, L0, nL);
    buildTab<12, 10, 660>(tw, ti, L0, nL);
    buildTab<12, 11, 820>(tw, ti, L0, nL);
    __syncthreads();

    // j<=7 batch correction of rows: 2 mid-evals per 16-row segment, linear apply.
    for (int w = threadIdx.x; w < nSeg * 32; w += 512) {
        const int s = w >> 5, cc = w & 31;
        const int rg = L0 + s * 16;
        float c0 = 0.f, c1 = 0.f;
#pragma unroll
        for (int j = 0; j < 8; ++j) {
            const int ptj = 1 << j;
            c0 += interp_pk(pk07 + (ptj - 1), ptj, (float)(2 * rg) + 0.5f, cc);
            c1 += interp_pk(pk07 + (ptj - 1), ptj, (float)(2 * rg + 2) + 0.5f, cc);
        }
        segA[s][cc] = c0;
        segB[s][cc] = c1 - c0;
    }
    __syncthreads();
    for (int rl = grp; rl < nL; rl += 16) {
        const int s = rl >> 4;
        Rl[rl * 32 + c] -= fmaf((float)(rl & 15), segB[s][c], segA[s][c]);
    }
    __syncthreads();

    cf_level<8>(Rl, bitsPyr, tw, ti, bits, pBig, b, L0, nL, r0, r1, c, grp, col);
    cf_level<9>(Rl, bitsPyr, tw, ti, bits, pBig, b, L0, nL, r0, r1, c, grp, col);
    cf_level<10>(Rl, bitsPyr, tw, ti, bits, pBig, b, L0, nL, r0, r1, c, grp, col);
    cf_level<11>(Rl, bitsPyr, tw, ti, bits, pBig, b, L0, nL, r0, r1, c, grp, col);
    cf_level<12>(Rl, bitsPyr, tw, ti, bits, pBig, b, L0, nL, r0, r1, c, grp, col);

    // ---- level 13 (fused final over this chunk's 256-t window) ----
    const int t0 = 2 * r0;
    const int p8 = L0 / 16, p9 = L0 / 8, p10 = L0 / 4, p11 = L0 / 2;
    for (int w = threadIdx.x; w < 16 * 32; w += 512) {
        const int s = w >> 5, cc = w & 31;
        const int tA = t0 + s * 16;
        float c0 = 0.f, c1 = 0.f;
#pragma unroll
        for (int j = 0; j < 8; ++j) {
            const int ptj = 1 << j;
            c0 += interp_pk(pk07 + (ptj - 1), ptj, (float)tA, cc);
            c1 += interp_pk(pk07 + (ptj - 1), ptj, (float)(tA + 1), cc);
        }
        c0 += interp_loc<256>(bitsPyr + 0, p8, (float)tA, cc);
        c1 += interp_loc<256>(bitsPyr + 0, p8, (float)(tA + 1), cc);
        segA[s][cc] = c0;
        segB[s][cc] = c1 - c0;
    }
    __syncthreads();
    const unsigned int* bl9 = bitsPyr + 10;
    const unsigned int* bl10 = bitsPyr + 30;
    const unsigned int* bl11 = bitsPyr + 70;
    const unsigned int* bl12 = bitsPyr + 150;
    float pAcc = 0.f, eAcc = 0.f, cAcc = 0.f;
    for (int j2 = grp; j2 < OWN; j2 += 16) {          // pair index
        const int mg = r0 + j2;
        const int lr = mg - L0;
        const int te = 2 * mg;
        const int tte = 2 * j2;
        const int s = tte >> 4;

        const int e9 = te & 15;
        int lo9 = (te >> 4) - 1 + (e9 >= 8 ? 1 : 0);
        float w9e = (e9 < 8 ? (float)(17 + 2 * e9) : (float)(2 * e9 - 15)) * (1.0f / 32.0f);
        float w9o = w9e + (1.0f / 16.0f);
        if (lo9 < 0) { lo9 = 0; w9e = 0.f; w9o = 0.f; }
        const int hi9 = min(lo9 + 1, 511);
        const float b9a = (float)((bl9[lo9 - p9] >> c) & 1u);
        const float b9b = (float)((bl9[hi9 - p9] >> c) & 1u);

        const int e10 = te & 7;
        int lo10 = (te >> 3) - 1 + (e10 >= 4 ? 1 : 0);
        float w10e = (e10 < 4 ? (float)(9 + 2 * e10) : (float)(2 * e10 - 7)) * (1.0f / 16.0f);
        float w10o = w10e + (1.0f / 8.0f);
        if (lo10 < 0) { lo10 = 0; w10e = 0.f; w10o = 0.f; }
        const int hi10 = min(lo10 + 1, 1023);
        const float b10a = (float)((bl10[lo10 - p10] >> c) & 1u);
        const float b10b = (float)((bl10[hi10 - p10] >> c) & 1u);

        const int e11 = te & 3;
        int lo11 = (te >> 2) - 1 + (e11 >= 2 ? 1 : 0);
        float w11e = (e11 < 2 ? (float)(5 + 2 * e11) : (float)(2 * e11 - 3)) * (1.0f / 8.0f);
        float w11o = w11e + (1.0f / 4.0f);
        if (lo11 < 0) { lo11 = 0; w11e = 0.f; w11o = 0.f; }
        const int hi11 = min(lo11 + 1, 2047);
        const float b11a = (float)((bl11[lo11 - p11] >> c) & 1u);
        const float b11b = (float)((bl11[hi11 - p11] >> c) & 1u);

        const float q12m1 = (float)((bl12[max(lr - 1, 0)] >> c) & 1u);
        const float q12z = (float)((bl12[lr] >> c) & 1u);
        const float q12p1 = (float)((bl12[min(lr + 1, nL - 1)] >> c) & 1u);
        const float w12e = (mg == 0) ? 0.f : 0.75f;
        const float w12o = 0.25f;

        float upe = fmaf((float)(tte & 15), segB[s][c], segA[s][c]);
        upe += ((b9a * (1.0f - w9e) + b9b * w9e) * 2.0f - 1.0f) * QSCALE;
        upe += ((b10a * (1.0f - w10e) + b10b * w10e) * 2.0f - 1.0f) * QSCALE;
        upe += ((b11a * (1.0f - w11e) + b11b * w11e) * 2.0f - 1.0f) * QSCALE;
        upe += ((q12m1 * (1.0f - w12e) + q12z * w12e) * 2.0f - 1.0f) * QSCALE;

        float upo = fmaf((float)((tte + 1) & 15), segB[s][c], segA[s][c]);
        upo += ((b9a * (1.0f - w9o) + b9b * w9o) * 2.0f - 1.0f) * QSCALE;
        upo += ((b10a * (1.0f - w10o) + b10b * w10o) * 2.0f - 1.0f) * QSCALE;
        upo += ((b11a * (1.0f - w11o) + b11b * w11o) * 2.0f - 1.0f) * QSCALE;
        upo += ((q12z * (1.0f - w12o) + q12p1 * w12o) * 2.0f - 1.0f) * QSCALE;

        {
            const size_t idx = ((size_t)b * T_DIM + te) * C_DIM + c;
            const float v = f[idx] - upe;
            float bit;
            const float zh = bsq_eval(v, bit, pAcc, eAcc, cAcc);
            bits[((size_t)b * SUM_PT + (T_DIM - 1) + te) * C_DIM + c] = bit;
            outQ[idx] = upe + zh;
        }
        {
            const size_t idx = ((size_t)b * T_DIM + te + 1) * C_DIM + c;
            const float v = f[idx] - upo;
            float bit;
            const float zh = bsq_eval(v, bit, pAcc, eAcc, cAcc);
            bits[((size_t)b * SUM_PT + (T_DIM - 1) + te + 1) * C_DIM + c] = bit;
            outQ[idx] = upo + zh;
        }
    }
    wave_partials(eAcc, cAcc, pAcc, pBig + (size_t)5 * 34 * PARTB, PARTB, col);
}

// ---------------------------------------------------------------------------
// Stage-1 reduce: one 64-thread block per (level, comp).
// ---------------------------------------------------------------------------
__global__ void reduce_partials(const float* __restrict__ pSm,
                                const float* __restrict__ pBig,
                                float* __restrict__ acc) {
    const int level = blockIdx.x / 34;
    const int comp = blockIdx.x % 34;
    const float* s;
    int n;
    if (level < 8) { s = pSm + ((size_t)level * 34 + comp) * PARTS; n = PARTS; }
    else { s = pBig + ((size_t)(level - 8) * 34 + comp) * PARTB; n = PARTB; }
    float v = 0.f;
    for (int i = threadIdx.x; i < n; i += 64) v += s[i];
#pragma unroll
    for (int m = 32; m >= 1; m >>= 1) v += __shfl_xor(v, m, 64);
    if (threadIdx.x == 0) acc[level * 34 + comp] = v;
}

__global__ void finalize_kernel(const float* __restrict__ acc, float* __restrict__ outL) {
    const int k = threadIdx.x >> 5;
    const int c = threadIdx.x & 31;
    if (k >= NLEVEL) return;
    const float cnt = (float)(B_DIM << k);
    const float avg_p = acc[k * 34 + 2 + c] / cnt;
    float ec = entf(avg_p) + entf(1.0f - avg_p);
#pragma unroll
    for (int m = 16; m >= 1; m >>= 1) ec += __shfl_xor(ec, m, 32);
    if (c == 0) {
        const float per_sample = acc[k * 34 + 0] / cnt;
        const float commit = acc[k * 34 + 1] / cnt;
        const float pen = (per_sample - ec) * (1.0f / 100.0f);
        outL[k] = pen * 0.1f + commit * 0.2f;
    }
}

extern "C" void kernel_launch(void* const* d_in, const int* in_sizes, int n_in,
                              void* d_out, int out_size, void* d_ws, size_t ws_size,
                              hipStream_t stream) {
    (void)in_sizes; (void)n_in; (void)out_size; (void)ws_size;
    const float* f = (const float*)d_in[0];
    float* outQ = (float*)d_out;                        // N_ELEM floats
    float* outBits = outQ + N_ELEM;                     // BITS_ELEM floats (0.0/1.0)
    float* outL = outBits + BITS_ELEM;                  // 14 floats

    float* pSm = (float*)d_ws;                          // 8*34*512 floats (~0.56MB)
    float* pBig = pSm + (size_t)8 * 34 * PARTS;         // 6*34*8192 floats (~6.7MB)
    float* acc = pBig + (size_t)6 * 34 * PARTB;         // 14*34 floats
    float* F128 = acc + NLEVEL * 34;                    // B*128*C floats (0.5MB)
    unsigned int* pkG = (unsigned int*)(F128 + (size_t)B_DIM * 128 * C_DIM); // B*256 words

    init_kernel<<<B_DIM * 128, 256, 0, stream>>>(f, F128);
    fused_small_kernel<<<B_DIM, 1024, 0, stream>>>(F128, outBits, pkG, pSm);
    chunk_final_kernel<<<B_DIM * 32, 512, 0, stream>>>(f, outQ, outBits, pkG, pBig);
    reduce_partials<<<NLEVEL * 34, 64, 0, stream>>>(pSm, pBig, acc);
    finalize_kernel<<<1, 512, 0, stream>>>(acc, outL);
}